// Round 1
// baseline (89.305 us; speedup 1.0000x reference)
//
#include <hip/hip_runtime.h>
#include <math.h>

// Problem constants (from the JAX reference)
#define IMG    14
#define HW     196       // 14*14 spatial positions
#define DEPTH  512       // channels C
#define NB     512       // batch
#define QS     49        // spatial positions per wave (196 / 4)
#define CTILE  64        // channels per block (one lane each)

// Block: 256 threads = 4 waves. Wave q owns spatial positions [q*49, q*49+49).
// Lane owns one channel. Grid: NB * (DEPTH/CTILE) = 512*8 = 4096 blocks.
__global__ __launch_bounds__(256) void mask_kernel(const float* __restrict__ x,
                                                   float* __restrict__ out) {
    const int tid   = threadIdx.x;
    const int lane  = tid & 63;   // channel within tile
    const int q     = tid >> 6;   // spatial quarter (also wave id)
    const int b     = blockIdx.x >> 3;
    const int ctile = blockIdx.x & 7;
    const int c     = (ctile << 6) + lane;

    // base address of (b, s=q*49, c)
    const size_t base = ((size_t)b * HW + (size_t)q * QS) * DEPTH + (size_t)c;
    const float* px = x + base;

    // ---- Pass: load 49 values into registers (coalesced 256B/wave/load) ----
    float v[QS];
#pragma unroll
    for (int k = 0; k < QS; ++k) {
        v[k] = px[(size_t)k * DEPTH];
    }

    // ---- Per-thread argmax over this quarter (first occurrence: strict >) ----
    float best = -INFINITY;
    int bestS = q * QS;
#pragma unroll
    for (int k = 0; k < QS; ++k) {
        if (v[k] > best) { best = v[k]; bestS = q * QS + k; }
    }

    // ---- Cross-wave reduction over the 4 quarters via LDS (2 KB) ----
    __shared__ float smax[4][CTILE];
    __shared__ int   sidx[4][CTILE];
    smax[q][lane] = best;
    sidx[q][lane] = bestS;
    __syncthreads();

    float m  = smax[0][lane];
    int   mi = sidx[0][lane];
#pragma unroll
    for (int r = 1; r < 4; ++r) {
        // quarters scanned in increasing spatial order; strict > keeps the
        // first occurrence, matching jnp.argmax tie semantics
        float vv = smax[r][lane];
        int   ii = sidx[r][lane];
        if (vv > m) { m = vv; mi = ii; }
    }

    // ---- Apply mask to register-held values and store (coalesced) ----
    const float fi  = (float)(mi / IMG);
    const float fj  = (float)(mi % IMG);
    const float TAU = (float)(0.5 / 196.0);

    float* po = out + base;
#pragma unroll
    for (int k = 0; k < QS; ++k) {
        const int s = q * QS + k;
        const float di   = fabsf((float)(s / IMG) - fi);
        const float dj   = fabsf((float)(s % IMG) - fj);
        const float dist = di + dj;                       // exact small int
        const float t    = fmaxf(1.0f - (4.0f * dist) / 14.0f, -1.0f);
        const float mask = TAU * t;                       // match ref op order
        po[(size_t)k * DEPTH] = v[k] * mask;
    }
}

extern "C" void kernel_launch(void* const* d_in, const int* in_sizes, int n_in,
                              void* d_out, int out_size, void* d_ws, size_t ws_size,
                              hipStream_t stream) {
    (void)in_sizes; (void)n_in; (void)out_size; (void)d_ws; (void)ws_size;
    const float* x = (const float*)d_in[0];
    float* out = (float*)d_out;
    dim3 grid(NB * (DEPTH / CTILE));  // 4096
    dim3 block(256);
    hipLaunchKernelGGL(mask_kernel, grid, block, 0, stream, x, out);
}